// Round 1
// baseline (1627.771 us; speedup 1.0000x reference)
//
#include <hip/hip_runtime.h>

#define IMH 512
#define IMW 512
#define NB 4
#define NPIX (IMH*IMW)

#define TX 64
#define TY 32
#define PW (TX+6)   // 70, p staged width (halo 3)
#define PH (TY+6)   // 38
#define RW (TX+4)   // 68, r staged width (halo 2)
#define RH (TY+4)   // 36
#define QW (TX+2)   // 66, p_new staged width (halo 1)
#define QH (TY+2)   // 34

// ginv = 1 + gx^2 + gy^2  (so denom = 1 + 0.125*mag*ginv == 1 + 0.125*mag/g)
__global__ __launch_bounds__(256) void init_kernel(
    const float* __restrict__ f, float* __restrict__ ginv,
    float* __restrict__ p1, float* __restrict__ p2, float* __restrict__ v) {
  int idx = blockIdx.x * blockDim.x + threadIdx.x;
  int total = NB * NPIX;
  for (; idx < total; idx += gridDim.x * blockDim.x) {
    int b = idx / NPIX;
    int rem = idx - b * NPIX;
    int y = rem / IMW, x = rem - y * IMW;
    const float* fb = f + b * NPIX;
    auto ld = [&](int yy, int xx) -> float {
      if (yy < 0 || yy >= IMH || xx < 0 || xx >= IMW) return 0.f;
      return fb[yy * IMW + xx];
    };
    float a00 = ld(y-1,x-1), a01 = ld(y-1,x), a02 = ld(y-1,x+1);
    float a10 = ld(y,  x-1),                  a12 = ld(y,  x+1);
    float a20 = ld(y+1,x-1), a21 = ld(y+1,x), a22 = ld(y+1,x+1);
    float gx = (a02 - a00) + 2.f*(a12 - a10) + (a22 - a20);
    float gy = (a20 - a00) + 2.f*(a21 - a01) + (a22 - a02);
    ginv[idx] = 1.f + gx*gx + gy*gy;
    p1[idx] = 0.f; p2[idx] = 0.f; v[idx] = 0.f;
  }
}

template <bool WRITE_U>
__global__ __launch_bounds__(256) void iter_kernel(
    const float* __restrict__ f, const float* __restrict__ ginv,
    const float* __restrict__ p1in, const float* __restrict__ p2in,
    const float* __restrict__ vin,
    float* __restrict__ p1out, float* __restrict__ p2out,
    float* __restrict__ vout, float* __restrict__ uout) {
  __shared__ float p1s[PH*PW];
  __shared__ float p2s[PH*PW];
  __shared__ float rs[RH*RW];
  __shared__ float q1[QH*QW];
  __shared__ float q2[QH*QW];

  const int b  = blockIdx.z;
  const int x0 = blockIdx.x * TX;
  const int y0 = blockIdx.y * TY;
  const int tid = threadIdx.x;
  const float* fb  = f     + b * NPIX;
  const float* gb  = ginv  + b * NPIX;
  const float* p1b = p1in  + b * NPIX;
  const float* p2b = p2in  + b * NPIX;
  const float* vb  = vin   + b * NPIX;

  // stage p1,p2 with halo 3 (zero outside image)
  for (int i = tid; i < PH*PW; i += 256) {
    int sy = i / PW, sx = i - sy * PW;
    int gy = y0 + sy - 3, gx = x0 + sx - 3;
    float a = 0.f, c = 0.f;
    if (gy >= 0 && gy < IMH && gx >= 0 && gx < IMW) {
      int o = gy * IMW + gx;
      a = p1b[o]; c = p2b[o];
    }
    p1s[i] = a; p2s[i] = c;
  }
  __syncthreads();

  // r = div_p - f + v over halo-2 region (zero outside image)
  for (int i = tid; i < RH*RW; i += 256) {
    int ry = i / RW, rx = i - ry * RW;
    int gy = y0 + ry - 2, gx = x0 + rx - 2;
    float val = 0.f;
    if (gy >= 0 && gy < IMH && gx >= 0 && gx < IMW) {
      int c = (ry + 1) * PW + (rx + 1);
      float divp = (p1s[c+1] - p1s[c-1]) + (p2s[c+PW] - p2s[c-PW]);
      int o = gy * IMW + gx;
      val = divp - fb[o] + vb[o];
    }
    rs[i] = val;
  }
  __syncthreads();

  // p_new over halo-1 region
  for (int i = tid; i < QH*QW; i += 256) {
    int qy = i / QW, qx = i - qy * QW;
    int gy = y0 + qy - 1, gx = x0 + qx - 1;
    float n1 = 0.f, n2 = 0.f;
    if (gy >= 0 && gy < IMH && gx >= 0 && gx < IMW) {
      int c = (qy + 1) * RW + (qx + 1);
      float rgx = ((rs[c-RW+1] - rs[c-RW-1]) + 2.f*(rs[c+1] - rs[c-1])
                 + (rs[c+RW+1] - rs[c+RW-1])) * 0.125f;
      float rgy = ((rs[c+RW-1] - rs[c-RW-1]) + 2.f*(rs[c+RW] - rs[c-RW])
                 + (rs[c+RW+1] - rs[c-RW+1])) * 0.125f;
      float gg = gb[gy * IMW + gx];
      float mag = sqrtf(rgx*rgx + rgy*rgy);
      float denom = 1.f + 0.125f * mag * gg;
      float inv = 1.f / denom;
      int pc = (qy + 2) * PW + (qx + 2);
      n1 = (p1s[pc] + 0.125f * rgx) * inv;
      n2 = (p2s[pc] + 0.125f * rgy) * inv;
    }
    q1[i] = n1; q2[i] = n2;
  }
  __syncthreads();

  // div(p_new), v update, (u on last iter), over owned tile
  for (int i = tid; i < TY*TX; i += 256) {
    int ty = i / TX, tx = i - ty * TX;
    int gy = y0 + ty, gx = x0 + tx;
    int o = gy * IMW + gx;
    int c = (ty + 1) * QW + (tx + 1);
    float divp = (q1[c+1] - q1[c-1]) + (q2[c+QW] - q2[c-QW]);
    float vold = vb[o];
    float diff = vold + divp;  // == f - u
    float vnew = diff > 0.1f ? diff - 0.1f : (diff < -0.1f ? diff + 0.1f : 0.f);
    int go = b * NPIX + o;
    p1out[go] = q1[c];
    p2out[go] = q2[c];
    vout[go]  = vnew;
    if (WRITE_U) uout[go] = fb[o] - vold - divp;
  }
}

extern "C" void kernel_launch(void* const* d_in, const int* in_sizes, int n_in,
                              void* d_out, int out_size, void* d_ws, size_t ws_size,
                              hipStream_t stream) {
  const float* f = (const float*)d_in[0];
  float* u = (float*)d_out;
  float* ws = (float*)d_ws;
  const size_t N = (size_t)NB * NPIX;
  // ws layout: ginv, p1a, p2a, va, p1b, p2b, vb  (7 * 4MB = 28MB)
  float* g   = ws + 0*N;
  float* p1a = ws + 1*N;
  float* p2a = ws + 2*N;
  float* va  = ws + 3*N;
  float* p1b = ws + 4*N;
  float* p2b = ws + 5*N;
  float* vb  = ws + 6*N;

  init_kernel<<<1024, 256, 0, stream>>>(f, g, p1a, p2a, va);

  dim3 grid(IMW / TX, IMH / TY, NB);
  for (int i = 0; i < 100; ++i) {
    const float *pi1, *pi2, *vi;
    float *po1, *po2, *vo;
    if ((i & 1) == 0) { pi1 = p1a; pi2 = p2a; vi = va; po1 = p1b; po2 = p2b; vo = vb; }
    else              { pi1 = p1b; pi2 = p2b; vi = vb; po1 = p1a; po2 = p2a; vo = va; }
    if (i == 99)
      iter_kernel<true ><<<grid, 256, 0, stream>>>(f, g, pi1, pi2, vi, po1, po2, vo, u);
    else
      iter_kernel<false><<<grid, 256, 0, stream>>>(f, g, pi1, pi2, vi, po1, po2, vo, nullptr);
  }
}

// Round 2
// 1088.071 us; speedup vs baseline: 1.4960x; 1.4960x over previous
//
#include <hip/hip_runtime.h>

#define IMH 512
#define IMW 512
#define NB 4
#define NPIX (IMH*IMW)

#define TX 64
#define TY 16

// 2-iteration fusion halo ladder:
// p_old@halo5 -> r1@halo4 -> p1@halo3 -> {v1,r2}@halo2 -> p2@halo1 -> out@halo0
#define AH (TY+10)   // 26  p_old (halo 5); reused for p2 (halo 1)
#define AW (TX+10)   // 74
#define DH (TY+8)    // 24  v_old (halo 4)
#define DW (TX+8)    // 72
#define CH (TY+8)    // 24  r1 (halo 4); reused for r2 (halo 2)
#define CW (TX+8)    // 72
#define BH (TY+6)    // 22  p1 (halo 3)
#define BW (TX+6)    // 70
#define EH (TY+4)    // 20  v1 (halo 2)
#define EW (TX+4)    // 68
#define R2W (TX+4)   // 68  r2 row width (overlaid on C)
#define QH (TY+2)    // 18  p2 (halo 1, overlaid on A)
#define QW (TX+2)    // 66

__device__ __forceinline__ float shrink01(float d) {
  return d > 0.1f ? d - 0.1f : (d < -0.1f ? d + 0.1f : 0.f);
}

// ginv = 1 + gx^2 + gy^2  (denom = 1 + 0.125*mag*ginv == 1 + 0.125*mag/g)
__global__ __launch_bounds__(256) void init_kernel(
    const float* __restrict__ f, float* __restrict__ ginv) {
  int idx = blockIdx.x * blockDim.x + threadIdx.x;
  int total = NB * NPIX;
  for (; idx < total; idx += gridDim.x * blockDim.x) {
    int b = idx / NPIX;
    int rem = idx - b * NPIX;
    int y = rem / IMW, x = rem - y * IMW;
    const float* fb = f + (size_t)b * NPIX;
    auto ld = [&](int yy, int xx) -> float {
      if (yy < 0 || yy >= IMH || xx < 0 || xx >= IMW) return 0.f;
      return fb[yy * IMW + xx];
    };
    float a00 = ld(y-1,x-1), a01 = ld(y-1,x), a02 = ld(y-1,x+1);
    float a10 = ld(y,  x-1),                  a12 = ld(y,  x+1);
    float a20 = ld(y+1,x-1), a21 = ld(y+1,x), a22 = ld(y+1,x+1);
    float gx = (a02 - a00) + 2.f*(a12 - a10) + (a22 - a20);
    float gy = (a20 - a00) + 2.f*(a21 - a01) + (a22 - a02);
    ginv[idx] = 1.f + gx*gx + gy*gy;
  }
}

template <bool FIRST, bool LAST>
__global__ __launch_bounds__(256) void iter2_kernel(
    const float* __restrict__ f, const float* __restrict__ ginv,
    const float* __restrict__ p1in, const float* __restrict__ p2in,
    const float* __restrict__ vin,
    float* __restrict__ p1out, float* __restrict__ p2out,
    float* __restrict__ vout, float* __restrict__ uout) {
  __shared__ float A1[AH*AW], A2[AH*AW];   // p_old, later p2
  __shared__ float B1[BH*BW], B2[BH*BW];   // p1
  __shared__ float Cs[CH*CW];              // r1, later r2
  __shared__ float Ds[DH*DW];              // v_old
  __shared__ float Es[EH*EW];              // v1

  // XCD-chunked bijective swizzle (gridDim.x = 1024, 1024 % 8 == 0):
  // each XCD gets a contiguous band of 128 virtual blocks.
  int phys = blockIdx.x;
  int virt = (phys & 7) * (int)(gridDim.x >> 3) + (phys >> 3);
  int bx = virt & 7;          // IMW/TX = 8
  int by = (virt >> 3) & 31;  // IMH/TY = 32
  int b  = virt >> 8;         // NB = 4

  const int x0 = bx * TX, y0 = by * TY;
  const int tid = threadIdx.x;
  const size_t boff = (size_t)b * NPIX;
  const float* fb  = f    + boff;
  const float* gb  = ginv + boff;
  const float* p1b = p1in + boff;
  const float* p2b = p2in + boff;
  const float* vb  = vin  + boff;

  // P0: stage p_old (halo 5) and v_old (halo 4); zero outside image
  for (int i = tid; i < AH*AW; i += 256) {
    int ly = i / AW, lx = i - ly*AW;
    int gy = y0 + ly - 5, gx = x0 + lx - 5;
    float a = 0.f, c = 0.f;
    if (!FIRST && gy >= 0 && gy < IMH && gx >= 0 && gx < IMW) {
      int o = gy*IMW + gx; a = p1b[o]; c = p2b[o];
    }
    A1[i] = a; A2[i] = c;
  }
  for (int i = tid; i < DH*DW; i += 256) {
    int ly = i / DW, lx = i - ly*DW;
    int gy = y0 + ly - 4, gx = x0 + lx - 4;
    float d = 0.f;
    if (!FIRST && gy >= 0 && gy < IMH && gx >= 0 && gx < IMW)
      d = vb[gy*IMW + gx];
    Ds[i] = d;
  }
  __syncthreads();

  // P1: r1 = div(p_old) - f + v_old over halo-4
  for (int i = tid; i < CH*CW; i += 256) {
    int ly = i / CW, lx = i - ly*CW;
    int gy = y0 + ly - 4, gx = x0 + lx - 4;
    float val = 0.f;
    if (gy >= 0 && gy < IMH && gx >= 0 && gx < IMW) {
      int a = (ly+1)*AW + (lx+1);
      float divp = (A1[a+1] - A1[a-1]) + (A2[a+AW] - A2[a-AW]);
      val = divp - fb[gy*IMW + gx] + Ds[i];
    }
    Cs[i] = val;
  }
  __syncthreads();

  // P2: p1 = (p_old + rg/8) / (1 + mag/8 * ginv) over halo-3
  for (int i = tid; i < BH*BW; i += 256) {
    int ly = i / BW, lx = i - ly*BW;
    int gy = y0 + ly - 3, gx = x0 + lx - 3;
    float n1 = 0.f, n2 = 0.f;
    if (gy >= 0 && gy < IMH && gx >= 0 && gx < IMW) {
      int c = (ly+1)*CW + (lx+1);
      float rgx = ((Cs[c-CW+1] - Cs[c-CW-1]) + 2.f*(Cs[c+1] - Cs[c-1])
                 + (Cs[c+CW+1] - Cs[c+CW-1])) * 0.125f;
      float rgy = ((Cs[c+CW-1] - Cs[c-CW-1]) + 2.f*(Cs[c+CW] - Cs[c-CW])
                 + (Cs[c+CW+1] - Cs[c-CW+1])) * 0.125f;
      float gg = gb[gy*IMW + gx];
      float denom = 1.f + 0.125f * __builtin_amdgcn_sqrtf(rgx*rgx + rgy*rgy) * gg;
      float inv = __builtin_amdgcn_rcpf(denom);
      int a = (ly+2)*AW + (lx+2);
      n1 = (A1[a] + 0.125f*rgx) * inv;
      n2 = (A2[a] + 0.125f*rgy) * inv;
    }
    B1[i] = n1; B2[i] = n2;
  }
  __syncthreads();

  // P3: v1 = shrink(v_old + div(p1)); r2 = div(p1) - f + v1  over halo-2
  for (int i = tid; i < EH*EW; i += 256) {
    int ly = i / EW, lx = i - ly*EW;
    int gy = y0 + ly - 2, gx = x0 + lx - 2;
    float vnew = 0.f, r2 = 0.f;
    if (gy >= 0 && gy < IMH && gx >= 0 && gx < IMW) {
      int bo = (ly+1)*BW + (lx+1);
      float divb = (B1[bo+1] - B1[bo-1]) + (B2[bo+BW] - B2[bo-BW]);
      float diff = Ds[(ly+2)*DW + (lx+2)] + divb;   // == f - u
      vnew = shrink01(diff);
      r2 = divb - fb[gy*IMW + gx] + vnew;
    }
    Es[i] = vnew;
    Cs[ly*R2W + lx] = r2;   // C reused (r1 dead)
  }
  __syncthreads();

  // P4: p2 over halo-1, stored into A (p_old dead)
  for (int i = tid; i < QH*QW; i += 256) {
    int ly = i / QW, lx = i - ly*QW;
    int gy = y0 + ly - 1, gx = x0 + lx - 1;
    float n1 = 0.f, n2 = 0.f;
    if (gy >= 0 && gy < IMH && gx >= 0 && gx < IMW) {
      int c = (ly+1)*R2W + (lx+1);
      float rgx = ((Cs[c-R2W+1] - Cs[c-R2W-1]) + 2.f*(Cs[c+1] - Cs[c-1])
                 + (Cs[c+R2W+1] - Cs[c+R2W-1])) * 0.125f;
      float rgy = ((Cs[c+R2W-1] - Cs[c-R2W-1]) + 2.f*(Cs[c+R2W] - Cs[c-R2W])
                 + (Cs[c+R2W+1] - Cs[c-R2W+1])) * 0.125f;
      float gg = gb[gy*IMW + gx];
      float denom = 1.f + 0.125f * __builtin_amdgcn_sqrtf(rgx*rgx + rgy*rgy) * gg;
      float inv = __builtin_amdgcn_rcpf(denom);
      int bo = (ly+2)*BW + (lx+2);
      n1 = (B1[bo] + 0.125f*rgx) * inv;
      n2 = (B2[bo] + 0.125f*rgy) * inv;
    }
    A1[ly*QW + lx] = n1; A2[ly*QW + lx] = n2;
  }
  __syncthreads();

  // P5: outputs over owned tile
  for (int i = tid; i < TY*TX; i += 256) {
    int ty = i / TX, tx = i - ty*TX;
    int gy = y0 + ty, gx = x0 + tx;
    int o = gy*IMW + gx;
    int q = (ty+1)*QW + (tx+1);
    float divp = (A1[q+1] - A1[q-1]) + (A2[q+QW] - A2[q-QW]);
    float vold = Es[(ty+2)*EW + (tx+2)];   // v1 (v before iter2's v-update)
    if (LAST) {
      uout[boff + o] = fb[o] - vold - divp;   // u = f - v - theta*div(p2)
    } else {
      float diff = vold + divp;
      p1out[boff + o] = A1[q];
      p2out[boff + o] = A2[q];
      vout[boff + o]  = shrink01(diff);
    }
  }
}

extern "C" void kernel_launch(void* const* d_in, const int* in_sizes, int n_in,
                              void* d_out, int out_size, void* d_ws, size_t ws_size,
                              hipStream_t stream) {
  const float* f = (const float*)d_in[0];
  float* u = (float*)d_out;
  float* ws = (float*)d_ws;
  const size_t N = (size_t)NB * NPIX;
  // ws layout: ginv, p1a, p2a, va, p1b, p2b, vb  (7 * 4MB = 28MB)
  float* g   = ws + 0*N;
  float* p1a = ws + 1*N;
  float* p2a = ws + 2*N;
  float* va  = ws + 3*N;
  float* p1b = ws + 4*N;
  float* p2b = ws + 5*N;
  float* vb  = ws + 6*N;

  init_kernel<<<512, 256, 0, stream>>>(f, g);

  const int NBLK = (IMW/TX) * (IMH/TY) * NB;   // 8*32*4 = 1024
  for (int l = 0; l < 50; ++l) {
    const float *pi1, *pi2, *vi;
    float *po1, *po2, *vo;
    if ((l & 1) == 0) { pi1 = p1a; pi2 = p2a; vi = va; po1 = p1b; po2 = p2b; vo = vb; }
    else              { pi1 = p1b; pi2 = p2b; vi = vb; po1 = p1a; po2 = p2a; vo = va; }
    if (l == 0)
      iter2_kernel<true, false><<<NBLK, 256, 0, stream>>>(f, g, pi1, pi2, vi, po1, po2, vo, nullptr);
    else if (l == 49)
      iter2_kernel<false, true><<<NBLK, 256, 0, stream>>>(f, g, pi1, pi2, vi, po1, po2, vo, u);
    else
      iter2_kernel<false, false><<<NBLK, 256, 0, stream>>>(f, g, pi1, pi2, vi, po1, po2, vo, nullptr);
  }
}